// Round 8
// baseline (394.228 us; speedup 1.0000x reference)
//
#include <hip/hip_runtime.h>
#include <stdint.h>

// Causal self-attention, B=8 T=2048 D=EMB=1024, fp32 in/out.
// Pipeline: x,W -> fp16; q/k/v proj (f16 MFMA); S=qk^T/32; E=exp(S) fp16
// (scores ~N(0,1), max ~5.5 -> no overflow; reference softmax is GLOBAL per
// batch so no max-shift); Z_b = sum(E); out = (E@v)/Z fp32.
//
// R8: big-wave-tile core. Diagnosis: all R2-R7 schedules pin at 880 TF
// because per-wave 128x64 tiles fix LDS frag traffic at 12KB/wave/K32
// (shape-invariant); serialized with MFMA -> util = 1242/2945 = 38%.
// Fix: 128x128 per wave (traffic x2/3) + 32x32x16 MFMA (2495 TF ceiling)
// -> 4-wave blocks, 1 wave/SIMD, acc 256 f32/lane (512-reg budget at
// __launch_bounds__(256,1)). Overlap: per tile {STG(t+2); vmcnt(8); bar;
// RD(t+1)->regs; MFMA(t)} - reads of t+1 are register-independent of
// MFMA(t), LDS service hides under MFMA. pv unchanged.

#define B_   8
#define T_   2048
#define DIM  1024

typedef _Float16 f16;
typedef f16   f16x8 __attribute__((ext_vector_type(8)));
typedef f16   f16x4 __attribute__((ext_vector_type(4)));
typedef float f32x4 __attribute__((ext_vector_type(4)));
typedef float f32x16 __attribute__((ext_vector_type(16)));

typedef const __attribute__((address_space(1))) void gvoid_t;
typedef __attribute__((address_space(3))) void lvoid_t;

// ================= staging/frag helpers =================
// 64-col layout (BK=64 pv core): 16B segments XOR-swizzled by (row&7).
__device__ __forceinline__ void stage_half256(const uint16_t* __restrict__ g, int ld,
                                              uint16_t* s, int tid) {
#pragma unroll
  for (int j = 0; j < 2; ++j) {
    int r   = j * 64 + (tid >> 3);
    int seg = (tid & 7) ^ (r & 7);
    const uint16_t* gp = g + (size_t)r * ld + seg * 8;
    uint16_t* sp = s + j * 4096 + (tid >> 6) * 512;  // wave-uniform; HW adds lane*16B
    __builtin_amdgcn_global_load_lds((gvoid_t*)gp, (lvoid_t*)sp, 16, 0, 0);
  }
}

__device__ __forceinline__ f16x8 frag64(const uint16_t* s, int r, int gseg) {
  return *(const f16x8*)(s + r * 64 + ((gseg ^ (r & 7)) * 8));
}

// 32-col layout: 4 segs/row, XOR by ((r>>1)&3): any 8 consecutive rows at a
// fixed seg hit all 8 16B bank-slots (verified conflict-free, R5/R6 counter
// = 0; 8-lane HW service groups read rows r..r+7 -> 8 distinct slots).
__device__ __forceinline__ f16x8 frag32(const uint16_t* s, int r, int gseg) {
  return *(const f16x8*)(s + r * 32 + ((gseg ^ ((r >> 1) & 3)) * 8));
}

// stage one 256x32 f16 tile (16KB) with 256 threads: 4 issues x 64 rows.
// LDS linear dest; global source pre-swizzled with the frag32 involution.
__device__ __forceinline__ void stage_t32(const uint16_t* __restrict__ g, int ld,
                                          uint16_t* s, int tid) {
#pragma unroll
  for (int j = 0; j < 4; ++j) {
    int r   = j * 64 + (tid >> 2);
    int seg = (tid & 3) ^ ((r >> 1) & 3);
    const uint16_t* gp = g + (size_t)r * ld + seg * 8;
    uint16_t* sp = s + j * 2048 + (tid >> 6) * 512;  // wave = 16 rows = 1KB
    __builtin_amdgcn_global_load_lds((gvoid_t*)gp, (lvoid_t*)sp, 16, 0, 0);
  }
}

__device__ __forceinline__ void lda4(const uint16_t* s, int rbase, int quad, int l15,
                                     f16x8 o[4][2]) {
#pragma unroll
  for (int mf = 0; mf < 4; ++mf) {
    int r = rbase + mf * 16 + l15;
#pragma unroll
    for (int kk = 0; kk < 2; ++kk) o[mf][kk] = frag64(s, r, kk * 4 + quad);
  }
}

__device__ __forceinline__ void ldb1(const uint16_t* s, int rbase, int quad, int l15,
                                     f16x8 o[2]) {
  int r = rbase + l15;
#pragma unroll
  for (int kk = 0; kk < 2; ++kk) o[kk] = frag64(s, r, kk * 4 + quad);
}

template <int M0, int N0>
__device__ __forceinline__ void mm8(f16x8 a[4][2], f16x8 b[2], f32x4 (&acc)[8][2]) {
#pragma unroll
  for (int kk = 0; kk < 2; ++kk)
#pragma unroll
    for (int mf = 0; mf < 4; ++mf)
      acc[M0 + mf][N0] = __builtin_amdgcn_mfma_f32_16x16x32_f16(
          a[mf][kk], b[kk], acc[M0 + mf][N0], 0, 0, 0);
}

#define SYNC_MFMA8(AA, BB, M0, N0)                     \
  __builtin_amdgcn_s_barrier();                        \
  asm volatile("s_waitcnt lgkmcnt(0)" ::: "memory");   \
  __builtin_amdgcn_s_setprio(1);                       \
  mm8<M0, N0>(AA, BB, acc);                            \
  __builtin_amdgcn_s_setprio(0);                       \
  __builtin_amdgcn_s_barrier();

// ---- R8 core: acc += A(256xK) @ B(256xK)^T, K = nT*32, nT even >= 4 ----
// 256 thr = 4 waves (2M x 2N), per-wave 128x128: acc[4][4] x f32x16 = 256.
// MFMA 32x32x16: A row = lane&31, k = (lane>>5)*8 + i (8 f16 = one b128);
// C/D: col = lane&31, row = (reg&3) + 8*(reg>>2) + 4*(lane>>5) [m74/m101].
// LDS 96KB: A[3][256][32] + B[3][256][32], rotating 3-buffer.
// Tile t: STG(t+2) issue; vmcnt(8) retires stage(t+1) (issued 1 tile ago);
// barrier (cross-wave visibility); RD(t+1) -> reg set; MFMA(t) on other
// set (no lgkm dep -> LDS service of RD overlaps MFMA). WAR on buf
// (t+2)%3=(t-1)%3: RD(t-1) completed >=1100 cyc before STG(t+2) data lands.
__device__ __forceinline__ void gemm256_w32(const uint16_t* __restrict__ gA,
                                            const uint16_t* __restrict__ gB,
                                            int lda, int ldb, int nT,
                                            uint16_t* smem, f32x16 (&acc)[4][4]) {
  const int tid = threadIdx.x, lane = tid & 63;
  const int l31 = lane & 31, half = lane >> 5;
  const int wv = tid >> 6, wr = wv >> 1, wc = wv & 1;

#define STG(tt)                                                          \
  { stage_t32(gA + (tt) * 32, lda, smem + ((tt) % 3) * 8192, tid);       \
    stage_t32(gB + (tt) * 32, ldb, smem + 24576 + ((tt) % 3) * 8192, tid); }

#define RD(tt, AV, BV)                                                   \
  { const uint16_t* sa = smem + ((tt) % 3) * 8192;                       \
    const uint16_t* sb = smem + 24576 + ((tt) % 3) * 8192;               \
    _Pragma("unroll")                                                    \
    for (int ks = 0; ks < 2; ++ks) {                                     \
      _Pragma("unroll")                                                  \
      for (int mt = 0; mt < 4; ++mt)                                     \
        AV[ks][mt] = frag32(sa, wr * 128 + mt * 32 + l31, ks * 2 + half);\
      _Pragma("unroll")                                                  \
      for (int nt = 0; nt < 4; ++nt)                                     \
        BV[ks][nt] = frag32(sb, wc * 128 + nt * 32 + l31, ks * 2 + half);\
    } }

#define MM(AV, BV)                                                       \
  { __builtin_amdgcn_s_setprio(1);                                       \
    _Pragma("unroll")                                                    \
    for (int ks = 0; ks < 2; ++ks)                                       \
      _Pragma("unroll")                                                  \
      for (int mt = 0; mt < 4; ++mt)                                     \
        _Pragma("unroll")                                                \
        for (int nt = 0; nt < 4; ++nt)                                   \
          acc[mt][nt] = __builtin_amdgcn_mfma_f32_32x32x16_f16(          \
              AV[ks][mt], BV[ks][nt], acc[mt][nt], 0, 0, 0);             \
    __builtin_amdgcn_s_setprio(0); }

  // prologue: stage(0), stage(1); retire stage(0); preload frags(0).
  STG(0)
  STG(1)
  asm volatile("s_waitcnt vmcnt(8)" ::: "memory");
  __builtin_amdgcn_s_barrier();

  f16x8 aA[2][4], bA[2][4], aB[2][4], bB[2][4];
  RD(0, aA, bA)
#pragma unroll 1
  for (int it = 0; it < (nT - 2) / 2; ++it) {
    const int t = 2 * it;
    STG(t + 2)
    asm volatile("s_waitcnt vmcnt(8)" ::: "memory");
    __builtin_amdgcn_s_barrier();
    RD(t + 1, aB, bB)
    MM(aA, bA)
    STG(t + 3)
    asm volatile("s_waitcnt vmcnt(8)" ::: "memory");
    __builtin_amdgcn_s_barrier();
    RD(t + 2, aA, bA)
    MM(aB, bB)
  }
  // epilogue: stage(nT-1) is the only outstanding group.
  asm volatile("s_waitcnt vmcnt(0)" ::: "memory");
  __builtin_amdgcn_s_barrier();
  RD(nT - 1, aB, bB)
  MM(aA, bA)
  MM(aB, bB)
#undef STG
#undef RD
#undef MM
}

// ---- NF=1 BK=64 core (pv, unchanged): acc += A(256xK) @ B(128xK)^T ----
__device__ __forceinline__ void gemm256n128_8ph(const uint16_t* __restrict__ gA,
                                                const uint16_t* __restrict__ gB,
                                                int lda, int ldb, int nIter,
                                                uint16_t* smem, f32x4 (&acc)[8][2]) {
  const int tid = threadIdx.x, lane = tid & 63;
  const int quad = lane >> 4, l15 = lane & 15;
  const int wv = tid >> 6, wr = wv >> 2, wc = wv & 3;

  uint16_t* sA0 = smem;
  uint16_t* sA1 = smem + 16384;
  uint16_t* sB0 = smem + 32768;
  uint16_t* sB1 = smem + 40960;

  stage_half256(gA,                     lda, sA0,        tid);
  stage_half256(gA + 128 * (size_t)lda, lda, sA0 + 8192, tid);
  stage_half256(gB,                     ldb, sB0,        tid);
  stage_half256(gB + 64,                ldb, sB1,        tid);
  asm volatile("s_waitcnt vmcnt(2)" ::: "memory");
  __builtin_amdgcn_s_barrier();

  f16x8 alo[4][2], ahi[4][2], b0[2], b1[2];
#pragma unroll 1
  for (int it = 0; it < nIter - 1; ++it) {
    const int t1 = 2 * it + 1, t2 = 2 * it + 2, t3 = 2 * it + 3;
    const uint16_t* gA1 = gA + t1 * 64;
    const uint16_t* gA2 = gA + t2 * 64;

    lda4(sA0, wr * 128,      quad, l15, alo);
    ldb1(sB0, wc * 32,       quad, l15, b0);
    stage_half256(gA1, lda, sA1, tid);
    SYNC_MFMA8(alo, b0, 0, 0)
    ldb1(sB0, wc * 32 + 16,  quad, l15, b1);
    stage_half256(gA1 + 128 * (size_t)lda, lda, sA1 + 8192, tid);
    SYNC_MFMA8(alo, b1, 0, 1)
    lda4(sA0, wr * 128 + 64, quad, l15, ahi);
    stage_half256(gB + t2 * 64, ldb, sB0, tid);
    SYNC_MFMA8(ahi, b1, 4, 1)
    asm volatile("s_waitcnt vmcnt(2)" ::: "memory");
    SYNC_MFMA8(ahi, b0, 4, 0)
    lda4(sA1, wr * 128,      quad, l15, alo);
    ldb1(sB1, wc * 32,       quad, l15, b0);
    stage_half256(gA2, lda, sA0, tid);
    SYNC_MFMA8(alo, b0, 0, 0)
    ldb1(sB1, wc * 32 + 16,  quad, l15, b1);
    stage_half256(gA2 + 128 * (size_t)lda, lda, sA0 + 8192, tid);
    SYNC_MFMA8(alo, b1, 0, 1)
    lda4(sA1, wr * 128 + 64, quad, l15, ahi);
    stage_half256(gB + t3 * 64, ldb, sB1, tid);
    SYNC_MFMA8(ahi, b1, 4, 1)
    asm volatile("s_waitcnt vmcnt(2)" ::: "memory");
    SYNC_MFMA8(ahi, b0, 4, 0)
  }
  {
    const uint16_t* gA1 = gA + (2 * nIter - 1) * 64;
    lda4(sA0, wr * 128,      quad, l15, alo);
    ldb1(sB0, wc * 32,       quad, l15, b0);
    stage_half256(gA1, lda, sA1, tid);
    SYNC_MFMA8(alo, b0, 0, 0)
    ldb1(sB0, wc * 32 + 16,  quad, l15, b1);
    stage_half256(gA1 + 128 * (size_t)lda, lda, sA1 + 8192, tid);
    SYNC_MFMA8(alo, b1, 0, 1)
    lda4(sA0, wr * 128 + 64, quad, l15, ahi);
    SYNC_MFMA8(ahi, b1, 4, 1)
    asm volatile("s_waitcnt vmcnt(0)" ::: "memory");
    SYNC_MFMA8(ahi, b0, 4, 0)
    lda4(sA1, wr * 128,      quad, l15, alo);
    ldb1(sB1, wc * 32,       quad, l15, b0);
    SYNC_MFMA8(alo, b0, 0, 0)
    ldb1(sB1, wc * 32 + 16,  quad, l15, b1);
    SYNC_MFMA8(alo, b1, 0, 1)
    lda4(sA1, wr * 128 + 64, quad, l15, ahi);
    SYNC_MFMA8(ahi, b1, 4, 1)
    SYNC_MFMA8(ahi, b0, 4, 0)
  }
}

// ---------------- helpers ----------------

__global__ void zero_lrow_kernel(float* __restrict__ lrow) {
  lrow[blockIdx.x * 256 + threadIdx.x] = 0.f;
}

__global__ void conv_x_kernel(const float* __restrict__ x, f16* __restrict__ xf) {
  size_t i = (size_t)blockIdx.x * 256 + threadIdx.x;
  float4 v = ((const float4*)x)[i];
  f16x4 o = {(f16)v.x, (f16)v.y, (f16)v.z, (f16)v.w};
  ((f16x4*)xf)[i] = o;
}

// W [K][N] fp32 -> WT fp16 [z][N][K]
__global__ void convT_w_kernel(const float* __restrict__ Wq, const float* __restrict__ Wk,
                               const float* __restrict__ Wv, f16* __restrict__ WT) {
  __shared__ float tile[64][65];
  const int z = blockIdx.z;
  const float* W = (z == 0) ? Wq : (z == 1) ? Wk : Wv;
  const int r0 = blockIdx.x * 64, c0 = blockIdx.y * 64, tid = threadIdx.x;
#pragma unroll
  for (int i = 0; i < 16; ++i) {
    int rr = (tid >> 6) + 4 * i, cc = tid & 63;
    tile[rr][cc] = W[(size_t)(r0 + rr) * DIM + c0 + cc];
  }
  __syncthreads();
#pragma unroll
  for (int i = 0; i < 16; ++i) {
    int nn = (tid >> 6) + 4 * i, kk = tid & 63;
    WT[(size_t)z * DIM * DIM + (size_t)(c0 + nn) * DIM + r0 + kk] = (f16)tile[kk][nn];
  }
}

__global__ void reduce_z_kernel(const float* __restrict__ lrow, float* __restrict__ invZ) {
  const int b = blockIdx.x, tid = threadIdx.x;
  float s = 0.f;
  for (int i = tid; i < T_; i += 256) s += lrow[(size_t)b * T_ + i];
#pragma unroll
  for (int off = 1; off < 64; off <<= 1) s += __shfl_xor(s, off, 64);
  __shared__ float red[4];
  if ((tid & 63) == 0) red[tid >> 6] = s;
  __syncthreads();
  if (tid == 0) invZ[b] = 1.0f / (red[0] + red[1] + red[2] + red[3]);
}

// ---------------- main kernels ----------------

// [16384,1024] x [1024,1024]^T + bias, 256x256 tiles, R8 4-wave core.
// Job order: XCD x owns A panels bx in [8x,8x+8), cycles 12 (z,by) combos.
__global__ __launch_bounds__(256, 1) void proj_kernel(
    const f16* __restrict__ xf, const f16* __restrict__ WT,
    const float* __restrict__ bq, const float* __restrict__ bk, const float* __restrict__ bv,
    f16* __restrict__ q, f16* __restrict__ k, f16* __restrict__ vT) {
  __shared__ uint16_t smem[49152];  // 96 KB

  const int bid = blockIdx.x;
  const int xcd = bid & 7, local = bid >> 3;     // local in [0,96)
  const int bx = xcd * 8 + (local & 7);
  const int zy = local >> 3;                     // 0..11
  const int z = zy >> 2, by = zy & 3;
  const size_t arow = (size_t)bx * 256;
  const int    bcol = by * 256;

  f32x16 acc[4][4];
#pragma unroll
  for (int i = 0; i < 4; ++i)
#pragma unroll
    for (int j = 0; j < 4; ++j) acc[i][j] = (f32x16)(0.f);

  gemm256_w32((const uint16_t*)xf + arow * DIM,
              (const uint16_t*)WT + (size_t)z * DIM * DIM + (size_t)bcol * DIM,
              DIM, DIM, 32, smem, acc);

  const float* bias = (z == 0) ? bq : (z == 1) ? bk : bv;
  const int tid = threadIdx.x, lane = tid & 63;
  const int l31 = lane & 31, half = lane >> 5;
  const int wv = tid >> 6, wr = wv >> 1, wc = wv & 1;
  if (z < 2) {
    f16* O = z ? k : q;
#pragma unroll
    for (int mt = 0; mt < 4; ++mt)
#pragma unroll
      for (int nt = 0; nt < 4; ++nt) {
        int n = bcol + wc * 128 + nt * 32 + l31;
        float bb = bias[n];
#pragma unroll
        for (int g = 0; g < 16; ++g) {
          size_t row = arow + wr * 128 + mt * 32 + (g & 3) + 8 * (g >> 2) + 4 * half;
          O[row * DIM + n] = (f16)(acc[mt][nt][g] + bb);
        }
      }
  } else {
#pragma unroll
    for (int mt = 0; mt < 4; ++mt)
#pragma unroll
      for (int nt = 0; nt < 4; ++nt) {
        int n = bcol + wc * 128 + nt * 32 + l31;
        float bb = bias[n];
#pragma unroll
        for (int r4 = 0; r4 < 4; ++r4) {
          int row0 = (int)arow + wr * 128 + mt * 32 + 8 * r4 + 4 * half;  // 4-aligned
          int bb_i = row0 >> 11, t0 = row0 & 2047;
          f16x4 pk;
#pragma unroll
          for (int rl = 0; rl < 4; ++rl) pk[rl] = (f16)(acc[mt][nt][r4 * 4 + rl] + bb);
          *(f16x4*)(vT + ((size_t)bb_i * DIM + n) * T_ + t0) = pk;
        }
      }
  }
}

// E = exp((q k^T)/32) with causal mask, fp16; per-row sums -> lrow (fp32
// atomics). 256^2 tiles: 36 causal tiles/batch, XCD b == batch b (288 wgs).
__global__ __launch_bounds__(256, 1) void scores_kernel(
    const f16* __restrict__ q, const f16* __restrict__ k,
    f16* __restrict__ E, float* __restrict__ lrow) {
  __shared__ uint16_t smem[49152];
  const int bid = blockIdx.x;
  const int b = bid & 7, tri = bid >> 3;         // tri in [0,36)
  int qi = 0;
  while ((qi + 1) * (qi + 2) / 2 <= tri) ++qi;   // qi in [0,8)
  const int ki = tri - qi * (qi + 1) / 2;

  f32x16 acc[4][4];
#pragma unroll
  for (int i = 0; i < 4; ++i)
#pragma unroll
    for (int j = 0; j < 4; ++j) acc[i][j] = (f32x16)(0.f);

  gemm256_w32((const uint16_t*)(q + ((size_t)b * T_ + qi * 256) * DIM),
              (const uint16_t*)(k + ((size_t)b * T_ + ki * 256) * DIM),
              DIM, DIM, 32, smem, acc);

  const int tid = threadIdx.x, lane = tid & 63;
  const int l31 = lane & 31, half = lane >> 5;
  const int wv = tid >> 6, wr = wv >> 1, wc = wv & 1;
  f16*   Eb = E + (size_t)b * T_ * T_;
  float* lb = lrow + (size_t)b * T_;
  const bool diag = (ki == qi);
#pragma unroll
  for (int mt = 0; mt < 4; ++mt) {
    float rs[16];
#pragma unroll
    for (int g = 0; g < 16; ++g) rs[g] = 0.f;
#pragma unroll
    for (int nt = 0; nt < 4; ++nt)
#pragma unroll
      for (int g = 0; g < 16; ++g) {
        int t = qi * 256 + wr * 128 + mt * 32 + (g & 3) + 8 * (g >> 2) + 4 * half;
        int s = ki * 256 + wc * 128 + nt * 32 + l31;
        float e = 0.f;
        if (!diag || s <= t) e = __expf(fminf(acc[mt][nt][g] * 0.03125f, 11.f));
        Eb[(size_t)t * T_ + s] = (f16)e;
        rs[g] += e;
      }
#pragma unroll
    for (int off = 1; off < 32; off <<= 1)
#pragma unroll
      for (int g = 0; g < 16; ++g) rs[g] += __shfl_xor(rs[g], off, 64);
    if (l31 == 0)
#pragma unroll
      for (int g = 0; g < 16; ++g)
        atomicAdd(&lb[qi * 256 + wr * 128 + mt * 32 + (g & 3) + 8 * (g >> 2) + 4 * half],
                  rs[g]);
  }
}

// out = (E @ v) * invZ, fp32. 256 wgs, XCD b == batch b. Block = (b, nt128,
// pair): qi=pair AND qi=7-pair -> uniform 18 half-width iterations.
__global__ __launch_bounds__(512, 2) void pv_kernel(
    const f16* __restrict__ E, const f16* __restrict__ vT,
    const float* __restrict__ invZ, float* __restrict__ out) {
  __shared__ uint16_t smem[49152];               // 96 KB
  const int bid = blockIdx.x;
  const int b = bid & 7, local = bid >> 3;       // local in [0,32)
  const int nt = local & 7, pair = local >> 3;   // nt: 128-col tile, pair in [0,4)

  const float iz = invZ[b];
  const int tid = threadIdx.x, lane = tid & 63, wv = tid >> 6;
  const int quad = lane >> 4, l15 = lane & 15;
  const int wr = wv >> 2, wc = wv & 3;
  float* ob = out + (size_t)b * T_ * DIM;
  const uint16_t* Bv = (const uint16_t*)(vT + ((size_t)b * DIM + nt * 128) * (size_t)T_);

#pragma unroll 1
  for (int j = 0; j < 2; ++j) {
    const int qi = j ? (7 - pair) : pair;
    f32x4 acc[8][2];
    {
      f32x4 z = {0.f, 0.f, 0.f, 0.f};
#pragma unroll
      for (int i = 0; i < 8; ++i) { acc[i][0] = z; acc[i][1] = z; }
    }
    gemm256n128_8ph((const uint16_t*)(E + ((size_t)b * T_ + qi * 256) * (size_t)T_),
                    Bv, T_, T_, (qi + 1) * 2, smem, acc);
#pragma unroll
    for (int mf = 0; mf < 8; ++mf)
#pragma unroll
      for (int nf = 0; nf < 2; ++nf)
#pragma unroll
        for (int r = 0; r < 4; ++r) {
          int t = qi * 256 + wr * 128 + mf * 16 + quad * 4 + r;
          int n = nt * 128 + wc * 32 + nf * 16 + l15;
          ob[(size_t)t * DIM + n] = acc[mf][nf][r] * iz;
        }
  }
}

// ---------------- launch ----------------

extern "C" void kernel_launch(void* const* d_in, const int* in_sizes, int n_in,
                              void* d_out, int out_size, void* d_ws, size_t ws_size,
                              hipStream_t stream) {
  const float* x  = (const float*)d_in[0];
  const float* Wq = (const float*)d_in[1];
  const float* bq = (const float*)d_in[2];
  const float* Wk = (const float*)d_in[3];
  const float* bk = (const float*)d_in[4];
  const float* Wv = (const float*)d_in[5];
  const float* bv = (const float*)d_in[6];
  float* out = (float*)d_out;

  char* ws = (char*)d_ws;
  // layout (bytes):
  f16*   E    = (f16*)ws;                     //  0 .. 67,108,864 (B*T*T fp16)
  f16*   xf   = (f16*)ws;                     //  alias: xf lives in E[0..SZ), dead before scores
  f16*   q    = (f16*)(ws + 67108864);        //  33,554,432
  f16*   k    = (f16*)(ws + 100663296);       //  33,554,432
  f16*   vT   = (f16*)(ws + 134217728);       //  33,554,432
  f16*   WT   = (f16*)(ws + 167772160);       //  6,291,456
  float* lrow = (float*)(ws + 174063616);     //  65,536
  float* invZ = (float*)(ws + 174129152);     //  32
  if (ws_size < (size_t)174129184) return;    // fail cleanly, not with a GPU fault

  zero_lrow_kernel<<<64, 256, 0, stream>>>(lrow);
  conv_x_kernel<<<16384, 256, 0, stream>>>(x, xf);
  convT_w_kernel<<<dim3(16, 16, 3), 256, 0, stream>>>(Wq, Wk, Wv, WT);
  proj_kernel<<<dim3(768), 256, 0, stream>>>(xf, WT, bq, bk, bv, q, k, vT);
  scores_kernel<<<dim3(288), 256, 0, stream>>>(q, k, E, lrow);
  reduce_z_kernel<<<B_, 256, 0, stream>>>(lrow, invZ);
  pv_kernel<<<dim3(256), 512, 0, stream>>>(E, vT, invZ, out);
}

// Round 9
// 338.125 us; speedup vs baseline: 1.1659x; 1.1659x over previous
//
#include <hip/hip_runtime.h>
#include <stdint.h>

// Causal self-attention, B=8 T=2048 D=EMB=1024, fp32 in/out.
// Pipeline: x,W -> fp16; q/k/v proj (f16 MFMA); S=qk^T/32; E=exp(S) fp16
// (scores ~N(0,1), max ~5.5 -> no overflow; reference softmax is GLOBAL per
// batch so no max-shift); Z_b = sum(E); out = (E@v)/Z fp32.
//
// R9: revert to R3 config (best measured, 346.7us) + two changes:
// (1) DROP the manual s_waitcnt lgkmcnt(0) before each MFMA cluster. It
// forced all 12 phase ds_reads to finish before the FIRST MFMA; compiler
// emits fine-grained per-use lgkmcnt(4/3/1/0) instead, so early MFMAs
// overlap the LDS service of later reads. Safety: compiler auto-waits
// guarantee operand readiness; all reads still complete before barrier-2
// (their MFMAs precede it), preserving the stage-write WAR ledger.
// (2) zero_lrow + conv_x + convT merged into one prep kernel (-2 launches).

#define B_   8
#define T_   2048
#define DIM  1024

typedef _Float16 f16;
typedef f16   f16x8 __attribute__((ext_vector_type(8)));
typedef f16   f16x4 __attribute__((ext_vector_type(4)));
typedef float f32x4 __attribute__((ext_vector_type(4)));

typedef const __attribute__((address_space(1))) void gvoid_t;
typedef __attribute__((address_space(3))) void lvoid_t;

// ================= staging/frag helpers =================
// 64-col layout: 16B segments XOR-swizzled by (row&7); conflict-free
// (2 lanes/bank-group on ds_read_b128; R2-R3 counters = 0).
__device__ __forceinline__ void stage_half256(const uint16_t* __restrict__ g, int ld,
                                              uint16_t* s, int tid) {
#pragma unroll
  for (int j = 0; j < 2; ++j) {
    int r   = j * 64 + (tid >> 3);
    int seg = (tid & 7) ^ (r & 7);
    const uint16_t* gp = g + (size_t)r * ld + seg * 8;
    uint16_t* sp = s + j * 4096 + (tid >> 6) * 512;  // wave-uniform; HW adds lane*16B
    __builtin_amdgcn_global_load_lds((gvoid_t*)gp, (lvoid_t*)sp, 16, 0, 0);
  }
}

__device__ __forceinline__ f16x8 frag64(const uint16_t* s, int r, int gseg) {
  return *(const f16x8*)(s + r * 64 + ((gseg ^ (r & 7)) * 8));
}

__device__ __forceinline__ void lda4(const uint16_t* s, int rbase, int quad, int l15,
                                     f16x8 o[4][2]) {
#pragma unroll
  for (int mf = 0; mf < 4; ++mf) {
    int r = rbase + mf * 16 + l15;
#pragma unroll
    for (int kk = 0; kk < 2; ++kk) o[mf][kk] = frag64(s, r, kk * 4 + quad);
  }
}

__device__ __forceinline__ void ldb2(const uint16_t* s, int rbase, int quad, int l15,
                                     f16x8 o[2][2]) {
#pragma unroll
  for (int nf = 0; nf < 2; ++nf) {
    int r = rbase + nf * 16 + l15;
#pragma unroll
    for (int kk = 0; kk < 2; ++kk) o[nf][kk] = frag64(s, r, kk * 4 + quad);
  }
}

__device__ __forceinline__ void ldb1(const uint16_t* s, int rbase, int quad, int l15,
                                     f16x8 o[2]) {
  int r = rbase + l15;
#pragma unroll
  for (int kk = 0; kk < 2; ++kk) o[kk] = frag64(s, r, kk * 4 + quad);
}

template <int M0, int N0>
__device__ __forceinline__ void mm16(f16x8 a[4][2], f16x8 b[2][2], f32x4 (&acc)[8][4]) {
#pragma unroll
  for (int kk = 0; kk < 2; ++kk)
#pragma unroll
    for (int mf = 0; mf < 4; ++mf)
#pragma unroll
      for (int nf = 0; nf < 2; ++nf)
        acc[M0 + mf][N0 + nf] = __builtin_amdgcn_mfma_f32_16x16x32_f16(
            a[mf][kk], b[nf][kk], acc[M0 + mf][N0 + nf], 0, 0, 0);
}

template <int M0, int N0>
__device__ __forceinline__ void mm8(f16x8 a[4][2], f16x8 b[2], f32x4 (&acc)[8][2]) {
#pragma unroll
  for (int kk = 0; kk < 2; ++kk)
#pragma unroll
    for (int mf = 0; mf < 4; ++mf)
      acc[M0 + mf][N0] = __builtin_amdgcn_mfma_f32_16x16x32_f16(
          a[mf][kk], b[kk], acc[M0 + mf][N0], 0, 0, 0);
}

// phase tail: barrier | prio-boosted MFMA cluster (compiler emits
// fine-grained lgkmcnt per MFMA operand - R9: no manual lgkm0) | barrier
#define SYNC_MFMA(AA, BB, M0, N0)                      \
  __builtin_amdgcn_s_barrier();                        \
  __builtin_amdgcn_s_setprio(1);                       \
  mm16<M0, N0>(AA, BB, acc);                           \
  __builtin_amdgcn_s_setprio(0);                       \
  __builtin_amdgcn_s_barrier();

#define SYNC_MFMA8(AA, BB, M0, N0)                     \
  __builtin_amdgcn_s_barrier();                        \
  __builtin_amdgcn_s_setprio(1);                       \
  mm8<M0, N0>(AA, BB, acc);                            \
  __builtin_amdgcn_s_setprio(0);                       \
  __builtin_amdgcn_s_barrier();

// ---- NF=2 core: acc += A(256xK) @ B(256xK)^T, K = nIter*128, nIter>=2 ----
// Steady state: vmcnt(4) at ph4/ph8 retires exactly the half-tiles the next
// buffer-switch reads (in-order retirement; 12 outstanding -> keep 4 newest).
// Tail iteration: only ph1/ph2 stages are live (t1); ph4 drains all (vmcnt 0).
__device__ __forceinline__ void gemm256_8ph(const uint16_t* __restrict__ gA,
                                            const uint16_t* __restrict__ gB,
                                            int lda, int ldb, int nIter,
                                            uint16_t* smem, f32x4 (&acc)[8][4]) {
  const int tid = threadIdx.x, lane = tid & 63;
  const int quad = lane >> 4, l15 = lane & 15;
  const int wv = tid >> 6, wr = wv >> 2, wc = wv & 3;   // wave grid 2M x 4N

  uint16_t* sA0 = smem;
  uint16_t* sA1 = smem + 16384;
  uint16_t* sB0 = smem + 32768;
  uint16_t* sB1 = smem + 49152;

  // prologue: tile0 -> buf0 (A,B); tile1.B -> buf1.B; keep 4 newest in flight.
  stage_half256(gA,                          lda, sA0,        tid);
  stage_half256(gA + 128 * (size_t)lda,      lda, sA0 + 8192, tid);
  stage_half256(gB,                          ldb, sB0,        tid);
  stage_half256(gB + 128 * (size_t)ldb,      ldb, sB0 + 8192, tid);
  stage_half256(gB + 64,                     ldb, sB1,        tid);
  stage_half256(gB + 64 + 128 * (size_t)ldb, ldb, sB1 + 8192, tid);
  asm volatile("s_waitcnt vmcnt(4)" ::: "memory");
  __builtin_amdgcn_s_barrier();

  f16x8 alo[4][2], ahi[4][2], blo[2][2], bhi[2][2];
#pragma unroll 1
  for (int it = 0; it < nIter - 1; ++it) {   // 2 K-tiles (BK=64) per iteration
    const int t1 = 2 * it + 1, t2 = 2 * it + 2, t3 = 2 * it + 3;  // <= 2*nIter-1
    const uint16_t* gA1 = gA + t1 * 64;
    const uint16_t* gA2 = gA + t2 * 64;
    const uint16_t* gB2 = gB + t2 * 64;
    const uint16_t* gB3 = gB + t3 * 64;

    // ph1: Q0 on buf0; stage buf1.Ah0 (t1)
    lda4(sA0, wr * 128,      quad, l15, alo);
    ldb2(sB0, wc * 64,       quad, l15, blo);
    stage_half256(gA1, lda, sA1, tid);
    SYNC_MFMA(alo, blo, 0, 0)
    // ph2: Q1; stage buf1.Ah1
    ldb2(sB0, wc * 64 + 32,  quad, l15, bhi);
    stage_half256(gA1 + 128 * (size_t)lda, lda, sA1 + 8192, tid);
    SYNC_MFMA(alo, bhi, 0, 2)
    // ph3: Q2; buf0.B free -> stage buf0.Bh0 (t2)
    lda4(sA0, wr * 128 + 64, quad, l15, ahi);
    stage_half256(gB2, ldb, sB0, tid);
    SYNC_MFMA(ahi, bhi, 4, 2)
    // ph4: Q3; stage buf0.Bh1; retire prev.Bh(sB1) + ph1/2 (sA1), keep 4
    stage_half256(gB2 + 128 * (size_t)ldb, ldb, sB0 + 8192, tid);
    asm volatile("s_waitcnt vmcnt(4)" ::: "memory");
    SYNC_MFMA(ahi, blo, 4, 0)
    // ph5: Q0 on buf1; stage buf0.Ah0 (t2)
    lda4(sA1, wr * 128,      quad, l15, alo);
    ldb2(sB1, wc * 64,       quad, l15, blo);
    stage_half256(gA2, lda, sA0, tid);
    SYNC_MFMA(alo, blo, 0, 0)
    // ph6: Q1; stage buf0.Ah1
    ldb2(sB1, wc * 64 + 32,  quad, l15, bhi);
    stage_half256(gA2 + 128 * (size_t)lda, lda, sA0 + 8192, tid);
    SYNC_MFMA(alo, bhi, 0, 2)
    // ph7: Q2; stage buf1.Bh0 (t3)
    lda4(sA1, wr * 128 + 64, quad, l15, ahi);
    stage_half256(gB3, ldb, sB1, tid);
    SYNC_MFMA(ahi, bhi, 4, 2)
    // ph8: Q3; stage buf1.Bh1; retire ph3/4 (sB0) + ph5/6 (sA0), keep 4
    stage_half256(gB3 + 128 * (size_t)ldb, ldb, sB1 + 8192, tid);
    asm volatile("s_waitcnt vmcnt(4)" ::: "memory");
    SYNC_MFMA(ahi, blo, 4, 0)
  }

  // tail iteration (tiles 2n-2, 2n-1): only t1 stages are live.
  {
    const uint16_t* gA1 = gA + (2 * nIter - 1) * 64;
    lda4(sA0, wr * 128,      quad, l15, alo);
    ldb2(sB0, wc * 64,       quad, l15, blo);
    stage_half256(gA1, lda, sA1, tid);
    SYNC_MFMA(alo, blo, 0, 0)
    ldb2(sB0, wc * 64 + 32,  quad, l15, bhi);
    stage_half256(gA1 + 128 * (size_t)lda, lda, sA1 + 8192, tid);
    SYNC_MFMA(alo, bhi, 0, 2)
    lda4(sA0, wr * 128 + 64, quad, l15, ahi);
    SYNC_MFMA(ahi, bhi, 4, 2)
    asm volatile("s_waitcnt vmcnt(0)" ::: "memory");   // sB1(prev ph7/8) + sA1
    SYNC_MFMA(ahi, blo, 4, 0)
    lda4(sA1, wr * 128,      quad, l15, alo);
    ldb2(sB1, wc * 64,       quad, l15, blo);
    SYNC_MFMA(alo, blo, 0, 0)
    ldb2(sB1, wc * 64 + 32,  quad, l15, bhi);
    SYNC_MFMA(alo, bhi, 0, 2)
    lda4(sA1, wr * 128 + 64, quad, l15, ahi);
    SYNC_MFMA(ahi, bhi, 4, 2)
    SYNC_MFMA(ahi, blo, 4, 0)
  }
}

// ---- NF=1 core: acc += A(256xK) @ B(128xK)^T, K = nIter*128, nIter>=2 ----
// LDS: A dbuf 2x32KB + B dbuf 2x16KB = 96KB. Per-wave 128x32.
__device__ __forceinline__ void gemm256n128_8ph(const uint16_t* __restrict__ gA,
                                                const uint16_t* __restrict__ gB,
                                                int lda, int ldb, int nIter,
                                                uint16_t* smem, f32x4 (&acc)[8][2]) {
  const int tid = threadIdx.x, lane = tid & 63;
  const int quad = lane >> 4, l15 = lane & 15;
  const int wv = tid >> 6, wr = wv >> 2, wc = wv & 3;

  uint16_t* sA0 = smem;
  uint16_t* sA1 = smem + 16384;
  uint16_t* sB0 = smem + 32768;   // 128x64 tile = 8192 u16
  uint16_t* sB1 = smem + 40960;

  stage_half256(gA,                     lda, sA0,        tid);
  stage_half256(gA + 128 * (size_t)lda, lda, sA0 + 8192, tid);
  stage_half256(gB,                     ldb, sB0,        tid);
  stage_half256(gB + 64,                ldb, sB1,        tid);
  asm volatile("s_waitcnt vmcnt(2)" ::: "memory");
  __builtin_amdgcn_s_barrier();

  f16x8 alo[4][2], ahi[4][2], b0[2], b1[2];
#pragma unroll 1
  for (int it = 0; it < nIter - 1; ++it) {
    const int t1 = 2 * it + 1, t2 = 2 * it + 2, t3 = 2 * it + 3;
    const uint16_t* gA1 = gA + t1 * 64;
    const uint16_t* gA2 = gA + t2 * 64;

    lda4(sA0, wr * 128,      quad, l15, alo);
    ldb1(sB0, wc * 32,       quad, l15, b0);
    stage_half256(gA1, lda, sA1, tid);
    SYNC_MFMA8(alo, b0, 0, 0)
    ldb1(sB0, wc * 32 + 16,  quad, l15, b1);
    stage_half256(gA1 + 128 * (size_t)lda, lda, sA1 + 8192, tid);
    SYNC_MFMA8(alo, b1, 0, 1)
    lda4(sA0, wr * 128 + 64, quad, l15, ahi);
    stage_half256(gB + t2 * 64, ldb, sB0, tid);
    SYNC_MFMA8(ahi, b1, 4, 1)
    asm volatile("s_waitcnt vmcnt(2)" ::: "memory");
    SYNC_MFMA8(ahi, b0, 4, 0)
    lda4(sA1, wr * 128,      quad, l15, alo);
    ldb1(sB1, wc * 32,       quad, l15, b0);
    stage_half256(gA2, lda, sA0, tid);
    SYNC_MFMA8(alo, b0, 0, 0)
    ldb1(sB1, wc * 32 + 16,  quad, l15, b1);
    stage_half256(gA2 + 128 * (size_t)lda, lda, sA0 + 8192, tid);
    SYNC_MFMA8(alo, b1, 0, 1)
    lda4(sA1, wr * 128 + 64, quad, l15, ahi);
    stage_half256(gB + t3 * 64, ldb, sB1, tid);
    SYNC_MFMA8(ahi, b1, 4, 1)
    asm volatile("s_waitcnt vmcnt(2)" ::: "memory");
    SYNC_MFMA8(ahi, b0, 4, 0)
  }
  {
    const uint16_t* gA1 = gA + (2 * nIter - 1) * 64;
    lda4(sA0, wr * 128,      quad, l15, alo);
    ldb1(sB0, wc * 32,       quad, l15, b0);
    stage_half256(gA1, lda, sA1, tid);
    SYNC_MFMA8(alo, b0, 0, 0)
    ldb1(sB0, wc * 32 + 16,  quad, l15, b1);
    stage_half256(gA1 + 128 * (size_t)lda, lda, sA1 + 8192, tid);
    SYNC_MFMA8(alo, b1, 0, 1)
    lda4(sA0, wr * 128 + 64, quad, l15, ahi);
    SYNC_MFMA8(ahi, b1, 4, 1)
    asm volatile("s_waitcnt vmcnt(0)" ::: "memory");
    SYNC_MFMA8(ahi, b0, 4, 0)
    lda4(sA1, wr * 128,      quad, l15, alo);
    ldb1(sB1, wc * 32,       quad, l15, b0);
    SYNC_MFMA8(alo, b0, 0, 0)
    ldb1(sB1, wc * 32 + 16,  quad, l15, b1);
    SYNC_MFMA8(alo, b1, 0, 1)
    lda4(sA1, wr * 128 + 64, quad, l15, ahi);
    SYNC_MFMA8(ahi, b1, 4, 1)
    SYNC_MFMA8(ahi, b0, 4, 0)
  }
}

__device__ __forceinline__ void zero_acc8(f32x4 (&acc)[8][4]) {
  f32x4 z = {0.f, 0.f, 0.f, 0.f};
#pragma unroll
  for (int i = 0; i < 8; ++i)
#pragma unroll
    for (int j = 0; j < 4; ++j) acc[i][j] = z;
}

// ---------------- prep: conv_x + convT_w + zero_lrow in one launch ----------------
// blocks [0,16384): x fp32 -> xf fp16 (float4/thread);
// blocks [16384,17152): W [K][N] fp32 -> WT fp16 [z][N][K] (64x64 tiles);
// blocks [17152,17216): lrow = 0.
__global__ void prep_kernel(const float* __restrict__ x, f16* __restrict__ xf,
                            const float* __restrict__ Wq, const float* __restrict__ Wk,
                            const float* __restrict__ Wv, f16* __restrict__ WT,
                            float* __restrict__ lrow) {
  const int bid = blockIdx.x, tid = threadIdx.x;
  if (bid < 16384) {
    size_t i = (size_t)bid * 256 + tid;
    float4 v = ((const float4*)x)[i];
    f16x4 o = {(f16)v.x, (f16)v.y, (f16)v.z, (f16)v.w};
    ((f16x4*)xf)[i] = o;
  } else if (bid < 17152) {
    __shared__ float tile[64][65];
    const int idx = bid - 16384;
    const int bx = idx & 15, by = (idx >> 4) & 15, z = idx >> 8;
    const float* W = (z == 0) ? Wq : (z == 1) ? Wk : Wv;
    const int r0 = bx * 64, c0 = by * 64;
#pragma unroll
    for (int i = 0; i < 16; ++i) {
      int rr = (tid >> 6) + 4 * i, cc = tid & 63;
      tile[rr][cc] = W[(size_t)(r0 + rr) * DIM + c0 + cc];
    }
    __syncthreads();
#pragma unroll
    for (int i = 0; i < 16; ++i) {
      int nn = (tid >> 6) + 4 * i, kk = tid & 63;
      WT[(size_t)z * DIM * DIM + (size_t)(c0 + nn) * DIM + r0 + kk] = (f16)tile[kk][nn];
    }
  } else {
    lrow[(size_t)(bid - 17152) * 256 + tid] = 0.f;
  }
}

__global__ void reduce_z_kernel(const float* __restrict__ lrow, float* __restrict__ invZ) {
  const int b = blockIdx.x, tid = threadIdx.x;
  float s = 0.f;
  for (int i = tid; i < T_; i += 256) s += lrow[(size_t)b * T_ + i];
#pragma unroll
  for (int off = 1; off < 64; off <<= 1) s += __shfl_xor(s, off, 64);
  __shared__ float red[4];
  if ((tid & 63) == 0) red[tid >> 6] = s;
  __syncthreads();
  if (tid == 0) invZ[b] = 1.0f / (red[0] + red[1] + red[2] + red[3]);
}

// ---------------- main kernels ----------------

// [16384,1024] x [1024,1024]^T + bias. z=0 -> q, z=1 -> k, z=2 -> vT.
// Job order: XCD x owns A panels bx in [8x,8x+8), cycles 12 (z,by) combos
// over them -> A L2-resident per XCD, WT (6MB total) from L2/L3.
__global__ __launch_bounds__(512, 2) void proj_kernel(
    const f16* __restrict__ xf, const f16* __restrict__ WT,
    const float* __restrict__ bq, const float* __restrict__ bk, const float* __restrict__ bv,
    f16* __restrict__ q, f16* __restrict__ k, f16* __restrict__ vT) {
  __shared__ uint16_t smem[65536];  // 128 KB

  const int bid = blockIdx.x;
  const int xcd = bid & 7, local = bid >> 3;     // local in [0,96)
  const int bx = xcd * 8 + (local & 7);
  const int zy = local >> 3;                     // 0..11
  const int z = zy >> 2, by = zy & 3;
  const size_t arow = (size_t)bx * 256;
  const int    bcol = by * 256;

  f32x4 acc[8][4];
  zero_acc8(acc);
  gemm256_8ph((const uint16_t*)xf + arow * DIM,
              (const uint16_t*)WT + (size_t)z * DIM * DIM + (size_t)bcol * DIM,
              DIM, DIM, 8, smem, acc);

  const float* bias = (z == 0) ? bq : (z == 1) ? bk : bv;
  const int tid = threadIdx.x, lane = tid & 63, wv = tid >> 6;
  const int quad = lane >> 4, l15 = lane & 15;
  const int wr = wv >> 2, wc = wv & 3;
  if (z < 2) {
    f16* O = z ? k : q;
#pragma unroll
    for (int mf = 0; mf < 8; ++mf)
#pragma unroll
      for (int nf = 0; nf < 4; ++nf) {
        int n = bcol + wc * 64 + nf * 16 + l15;
        float bb = bias[n];
        size_t row0 = arow + wr * 128 + mf * 16 + quad * 4;
#pragma unroll
        for (int r = 0; r < 4; ++r)
          O[(row0 + r) * DIM + n] = (f16)(acc[mf][nf][r] + bb);
      }
  } else {
#pragma unroll
    for (int mf = 0; mf < 8; ++mf)
#pragma unroll
      for (int nf = 0; nf < 4; ++nf) {
        int n = bcol + wc * 64 + nf * 16 + l15;
        float bb = bias[n];
        int row0 = (int)arow + wr * 128 + mf * 16 + quad * 4;  // 4-aligned, no batch straddle
        int bb_i = row0 >> 11, t0 = row0 & 2047;
        f16x4 pk;
#pragma unroll
        for (int r = 0; r < 4; ++r) pk[r] = (f16)(acc[mf][nf][r] + bb);
        *(f16x4*)(vT + ((size_t)bb_i * DIM + n) * T_ + t0) = pk;
      }
  }
}

// E = exp((q k^T)/32) with causal mask, fp16; per-row sums -> lrow (fp32
// atomics). 256^2 tiles: 36 causal tiles/batch, XCD b == batch b (288 wgs).
__global__ __launch_bounds__(512, 2) void scores_kernel(
    const f16* __restrict__ q, const f16* __restrict__ k,
    f16* __restrict__ E, float* __restrict__ lrow) {
  __shared__ uint16_t smem[65536];
  const int bid = blockIdx.x;
  const int b = bid & 7, tri = bid >> 3;         // tri in [0,36)
  int qi = 0;
  while ((qi + 1) * (qi + 2) / 2 <= tri) ++qi;   // qi in [0,8)
  const int ki = tri - qi * (qi + 1) / 2;

  f32x4 acc[8][4];
  zero_acc8(acc);
  gemm256_8ph((const uint16_t*)(q + ((size_t)b * T_ + qi * 256) * DIM),
              (const uint16_t*)(k + ((size_t)b * T_ + ki * 256) * DIM),
              DIM, DIM, 8, smem, acc);

  const int tid = threadIdx.x, lane = tid & 63, wv = tid >> 6;
  const int quad = lane >> 4, l15 = lane & 15;
  const int wr = wv >> 2, wc = wv & 3;
  f16*   Eb = E + (size_t)b * T_ * T_;
  float* lb = lrow + (size_t)b * T_;
  const bool diag = (ki == qi);
#pragma unroll
  for (int mf = 0; mf < 8; ++mf) {
    float rs[4] = {0.f, 0.f, 0.f, 0.f};
#pragma unroll
    for (int nf = 0; nf < 4; ++nf)
#pragma unroll
      for (int r = 0; r < 4; ++r) {
        int t = qi * 256 + wr * 128 + mf * 16 + quad * 4 + r;
        int s = ki * 256 + wc * 64 + nf * 16 + l15;
        float e = 0.f;
        if (!diag || s <= t) e = __expf(fminf(acc[mf][nf][r] * 0.03125f, 11.f));
        Eb[(size_t)t * T_ + s] = (f16)e;
        rs[r] += e;
      }
#pragma unroll
    for (int off = 1; off < 16; off <<= 1)
#pragma unroll
      for (int r = 0; r < 4; ++r) rs[r] += __shfl_xor(rs[r], off, 64);
    if (l15 == 0)
#pragma unroll
      for (int r = 0; r < 4; ++r)
        atomicAdd(&lb[qi * 256 + wr * 128 + mf * 16 + quad * 4 + r], rs[r]);
  }
}

// out = (E @ v) * invZ, fp32. 256 wgs, XCD b == batch b. Block = (b, nt128,
// pair): qi=pair AND qi=7-pair -> uniform 18 half-width iterations.
__global__ __launch_bounds__(512, 2) void pv_kernel(
    const f16* __restrict__ E, const f16* __restrict__ vT,
    const float* __restrict__ invZ, float* __restrict__ out) {
  __shared__ uint16_t smem[49152];               // 96 KB
  const int bid = blockIdx.x;
  const int b = bid & 7, local = bid >> 3;       // local in [0,32)
  const int nt = local & 7, pair = local >> 3;   // nt: 128-col tile, pair in [0,4)

  const float iz = invZ[b];
  const int tid = threadIdx.x, lane = tid & 63, wv = tid >> 6;
  const int quad = lane >> 4, l15 = lane & 15;
  const int wr = wv >> 2, wc = wv & 3;
  float* ob = out + (size_t)b * T_ * DIM;
  const uint16_t* Bv = (const uint16_t*)(vT + ((size_t)b * DIM + nt * 128) * (size_t)T_);

#pragma unroll 1
  for (int j = 0; j < 2; ++j) {
    const int qi = j ? (7 - pair) : pair;
    f32x4 acc[8][2];
    {
      f32x4 z = {0.f, 0.f, 0.f, 0.f};
#pragma unroll
      for (int i = 0; i < 8; ++i) { acc[i][0] = z; acc[i][1] = z; }
    }
    gemm256n128_8ph((const uint16_t*)(E + ((size_t)b * T_ + qi * 256) * (size_t)T_),
                    Bv, T_, T_, (qi + 1) * 2, smem, acc);
#pragma unroll
    for (int mf = 0; mf < 8; ++mf)
#pragma unroll
      for (int nf = 0; nf < 2; ++nf)
#pragma unroll
        for (int r = 0; r < 4; ++r) {
          int t = qi * 256 + wr * 128 + mf * 16 + quad * 4 + r;
          int n = nt * 128 + wc * 32 + nf * 16 + l15;
          ob[(size_t)t * DIM + n] = acc[mf][nf][r] * iz;
        }
  }
}

// ---------------- launch ----------------

extern "C" void kernel_launch(void* const* d_in, const int* in_sizes, int n_in,
                              void* d_out, int out_size, void* d_ws, size_t ws_size,
                              hipStream_t stream) {
  const float* x  = (const float*)d_in[0];
  const float* Wq = (const float*)d_in[1];
  const float* bq = (const float*)d_in[2];
  const float* Wk = (const float*)d_in[3];
  const float* bk = (const float*)d_in[4];
  const float* Wv = (const float*)d_in[5];
  const float* bv = (const float*)d_in[6];
  float* out = (float*)d_out;

  char* ws = (char*)d_ws;
  // layout (bytes):
  f16*   E    = (f16*)ws;                     //  0 .. 67,108,864 (B*T*T fp16)
  f16*   xf   = (f16*)ws;                     //  alias: xf lives in E[0..SZ), dead before scores
  f16*   q    = (f16*)(ws + 67108864);        //  33,554,432
  f16*   k    = (f16*)(ws + 100663296);       //  33,554,432
  f16*   vT   = (f16*)(ws + 134217728);       //  33,554,432
  f16*   WT   = (f16*)(ws + 167772160);       //  6,291,456
  float* lrow = (float*)(ws + 174063616);     //  65,536
  float* invZ = (float*)(ws + 174129152);     //  32
  if (ws_size < (size_t)174129184) return;    // fail cleanly, not with a GPU fault

  prep_kernel<<<17216, 256, 0, stream>>>(x, xf, Wq, Wk, Wv, WT, lrow);
  proj_kernel<<<dim3(768), 512, 0, stream>>>(xf, WT, bq, bk, bv, q, k, vT);
  scores_kernel<<<dim3(288), 512, 0, stream>>>(q, k, E, lrow);
  reduce_z_kernel<<<B_, 256, 0, stream>>>(lrow, invZ);
  pv_kernel<<<dim3(256), 512, 0, stream>>>(E, vT, invZ, out);
}